// Round 1
// 891.261 us; speedup vs baseline: 2.6645x; 2.6645x over previous
//
#include <hip/hip_runtime.h>
#include <math.h>

typedef __bf16 bf16;
typedef __attribute__((ext_vector_type(8))) __bf16 bf16x8;
typedef __attribute__((ext_vector_type(4))) float f32x4;

namespace {
constexpr int kB  = 128;
constexpr int kD  = 1024;
constexpr int kH1 = 512;
constexpr int kH2 = 256;
constexpr int kChunk = 16;   // batches per Vt/Mt scratch chunk
}

// async global->LDS, 16B per lane. LDS dest must be linear (base + lane*16);
// swizzled layouts are achieved by pre-swizzling the per-lane GLOBAL source.
__device__ __forceinline__ void gload16(const void* g, void* l) {
    __builtin_amdgcn_global_load_lds(
        (__attribute__((address_space(1))) void*)g,
        (__attribute__((address_space(3))) void*)l, 16, 0, 0);
}

// dst[c*R + r] = src[r*C + c]; optional bf16 copy of dst
__global__ void transpose_kernel(const float* __restrict__ src, float* __restrict__ dst,
                                 bf16* __restrict__ dstb, int R, int C) {
    __shared__ float tile[32][33];
    int c0 = blockIdx.x * 32, r0 = blockIdx.y * 32;
    int tx = threadIdx.x & 31, ty = threadIdx.x >> 5;  // 256 threads: ty 0..7
    #pragma unroll
    for (int i = ty; i < 32; i += 8)
        tile[i][tx] = src[(size_t)(r0 + i) * C + c0 + tx];
    __syncthreads();
    #pragma unroll
    for (int i = ty; i < 32; i += 8) {
        float v = tile[tx][i];
        dst[(size_t)(c0 + i) * R + r0 + tx] = v;
        if (dstb) dstb[(size_t)(c0 + i) * R + r0 + tx] = (bf16)v;
    }
}

// c = sigmoid(A[b,:] @ Bt[:,n] + bias[n]); optional second copy + s = c*(1-c)
// (forward pass stays fp32: recover/c2 are O(0.5), bf16 would cost ~1e-3 absmax)
__global__ void fwd_kernel(const float* __restrict__ A, const float* __restrict__ Bt,
                           const float* __restrict__ bias, int K, int N,
                           float* __restrict__ c_out, float* __restrict__ c2_out,
                           float* __restrict__ s_out) {
    int b = blockIdx.y;
    int n = blockIdx.x * 256 + threadIdx.x;
    if (n >= N) return;
    const float* a = A + (size_t)b * K;
    float acc0 = 0.f, acc1 = 0.f, acc2 = 0.f, acc3 = 0.f;
    #pragma unroll 4
    for (int k = 0; k < K; k += 4) {
        acc0 += a[k + 0] * Bt[(size_t)(k + 0) * N + n];
        acc1 += a[k + 1] * Bt[(size_t)(k + 1) * N + n];
        acc2 += a[k + 2] * Bt[(size_t)(k + 2) * N + n];
        acc3 += a[k + 3] * Bt[(size_t)(k + 3) * N + n];
    }
    float v = (acc0 + acc1) + (acc2 + acc3) + bias[n];
    float c = 1.0f / (1.0f + expf(-v));
    c_out[(size_t)b * N + n] = c;
    if (c2_out) c2_out[(size_t)b * N + n] = c;
    if (s_out)  s_out[(size_t)b * N + n] = c * (1.0f - c);
}

// MFMA stage 1 (bf16):
//   Vt[d,f] =            sum_h W1t[d,h] * (W2[f,h]*s1[b,h])
//   Mt[e,f] = s2[b,f] *  sum_h W1t[e,h] * (W2[f,h]*s3[b,h])
// Outputs stored [1024][256] bf16, f-contiguous (= K-major operands for stage 2).
// Tile 128(M=d) x 64(N=f), K-step 64, 4 waves (2x2), dual accumulators.
// LDS tiles: rows of 64 bf16 (128B), 16B-chunk XOR swizzle chunk^= (row&7).
__global__ __launch_bounds__(256) void vm_mfma_kernel(
    const bf16*  __restrict__ W1tb,  // [1024][512] bf16
    const float* __restrict__ W2,    // [256][512]
    const float* __restrict__ s1, const float* __restrict__ s2,
    const float* __restrict__ s3,
    bf16* __restrict__ Vt, bf16* __restrict__ Mt, int b0) {
    __shared__ __attribute__((aligned(16))) bf16 Al[128 * 64];
    __shared__ __attribute__((aligned(16))) bf16 Bv[64 * 64];
    __shared__ __attribute__((aligned(16))) bf16 Bm[64 * 64];
    const int bl = blockIdx.z, b = b0 + bl;
    const int d0 = blockIdx.x * 128;
    const int f0 = blockIdx.y * 64;
    const int tid = threadIdx.x;
    const int lane = tid & 63, w = tid >> 6;
    const int wm = (w >> 1) * 64, wn = (w & 1) * 32;   // wave tile 64x32
    const int lrow = lane & 15, lkg = lane >> 4;

    f32x4 accv[4][2] = {};
    f32x4 accm[4][2] = {};

    const int ar = tid >> 3;   // staging row within 32-row issue
    const int ac = tid & 7;    // staging 16B chunk slot
    const int bf = tid & 63;   // B staging: f row
    const int hb = tid >> 6;   // B staging: h-quarter (16 floats)

    for (int h0 = 0; h0 < kH1; h0 += 64) {
        // A tile: W1tb rows d0..d0+127, cols h0..h0+63 -> linear LDS,
        // source pre-swizzled so LDS slot c' holds logical chunk c'^(r&7).
        #pragma unroll
        for (int i = 0; i < 4; i++) {
            int r = i * 32 + ar;
            const bf16* src = W1tb + (size_t)(d0 + r) * kH1 + h0 + ((ac ^ (r & 7)) << 3);
            gload16(src, (char*)Al + i * 4096 + tid * 16);
        }
        // B tiles: W2 row * s1/s3, fp32 mul -> bf16, swizzled ds_write_b128
        {
            const float* wrow = W2 + (size_t)(f0 + bf) * kH1 + h0 + hb * 16;
            const float* s1p  = s1 + (size_t)b * kH1 + h0 + hb * 16;
            const float* s3p  = s3 + (size_t)b * kH1 + h0 + hb * 16;
            union F16 { float f[16]; float4 v[4]; } wv, x1, x3;
            #pragma unroll
            for (int q = 0; q < 4; q++) {
                wv.v[q] = *(const float4*)(wrow + q * 4);
                x1.v[q] = *(const float4*)(s1p + q * 4);
                x3.v[q] = *(const float4*)(s3p + q * 4);
            }
            #pragma unroll
            for (int q = 0; q < 2; q++) {
                union P8 { bf16 e[8]; bf16x8 v; } pv, pm;
                #pragma unroll
                for (int j = 0; j < 8; j++) {
                    int idx = q * 8 + j;
                    pv.e[j] = (bf16)(wv.f[idx] * x1.f[idx]);
                    pm.e[j] = (bf16)(wv.f[idx] * x3.f[idx]);
                }
                int c   = hb * 2 + q;
                int off = bf * 64 + ((c ^ (bf & 7)) << 3);
                *(bf16x8*)&Bv[off] = pv.v;
                *(bf16x8*)&Bm[off] = pm.v;
            }
        }
        __syncthreads();   // drains vmcnt (gload_lds) + lgkmcnt (ds_write)
        #pragma unroll
        for (int ks = 0; ks < 2; ks++) {
            const int cg = ks * 4 + lkg;   // lane's 16B chunk along K
            bf16x8 a[4], bv[2], bm[2];
            #pragma unroll
            for (int i = 0; i < 4; i++) {
                int r = wm + i * 16 + lrow;
                a[i] = *(const bf16x8*)&Al[r * 64 + ((cg ^ (r & 7)) << 3)];
            }
            #pragma unroll
            for (int j = 0; j < 2; j++) {
                int r = wn + j * 16 + lrow;
                int off = r * 64 + ((cg ^ (r & 7)) << 3);
                bv[j] = *(const bf16x8*)&Bv[off];
                bm[j] = *(const bf16x8*)&Bm[off];
            }
            #pragma unroll
            for (int i = 0; i < 4; i++)
                #pragma unroll
                for (int j = 0; j < 2; j++) {
                    accv[i][j] = __builtin_amdgcn_mfma_f32_16x16x32_bf16(a[i], bv[j], accv[i][j], 0, 0, 0);
                    accm[i][j] = __builtin_amdgcn_mfma_f32_16x16x32_bf16(a[i], bm[j], accm[i][j], 0, 0, 0);
                }
        }
        __syncthreads();
    }
    // epilogue: C/D frag -> Vt/Mt bf16; col = f (lane&15), rows = d
    #pragma unroll
    for (int j = 0; j < 2; j++) {
        int f = f0 + wn + j * 16 + lrow;
        float s2v = s2[(size_t)b * kH2 + f];
        #pragma unroll
        for (int i = 0; i < 4; i++)
            #pragma unroll
            for (int t = 0; t < 4; t++) {
                int d = d0 + wm + i * 16 + lkg * 4 + t;
                size_t off = ((size_t)bl * kD + d) * kH2 + f;
                Vt[off] = (bf16)accv[i][j][t];
                Mt[off] = (bf16)(accm[i][j][t] * s2v);
            }
    }
}

// MFMA stage 2 (bf16): Jst[d,e] = sum_f Vt[d,f] * Mt[e,f]
// Tile 128x128, K=256 in 4 steps of 64, 4 waves (2x2), both operands via
// global_load_lds (K-major bf16). Permuted fp32 row write (verified layout):
//   jac[((d>>3)<<10) + ((d&7)<<7) + b][e]
__global__ __launch_bounds__(256) void jac_mfma_kernel(
    const bf16* __restrict__ Vt, const bf16* __restrict__ Mt,
    float* __restrict__ jac, int b0) {
    __shared__ __attribute__((aligned(16))) bf16 Al[128 * 64];
    __shared__ __attribute__((aligned(16))) bf16 Bl[128 * 64];
    const int bl = blockIdx.z, b = b0 + bl;
    const int e0 = blockIdx.x * 128;
    const int d0 = blockIdx.y * 128;
    const int tid = threadIdx.x;
    const int lane = tid & 63, w = tid >> 6;
    const int wm = (w >> 1) * 64, wn = (w & 1) * 64;   // wave tile 64x64
    const int lrow = lane & 15, lkg = lane >> 4;
    const bf16* Vb = Vt + (size_t)bl * kD * kH2;
    const bf16* Mb = Mt + (size_t)bl * kD * kH2;

    f32x4 acc[4][4] = {};
    const int ar = tid >> 3, ac = tid & 7;

    for (int k0 = 0; k0 < kH2; k0 += 64) {
        #pragma unroll
        for (int i = 0; i < 4; i++) {
            int r = i * 32 + ar;
            int sc = (ac ^ (r & 7)) << 3;
            gload16(Vb + (size_t)(d0 + r) * kH2 + k0 + sc, (char*)Al + i * 4096 + tid * 16);
            gload16(Mb + (size_t)(e0 + r) * kH2 + k0 + sc, (char*)Bl + i * 4096 + tid * 16);
        }
        __syncthreads();
        #pragma unroll
        for (int ks = 0; ks < 2; ks++) {
            const int cg = ks * 4 + lkg;
            bf16x8 a[4], bb[4];
            #pragma unroll
            for (int i = 0; i < 4; i++) {
                int r1 = wm + i * 16 + lrow;
                a[i]  = *(const bf16x8*)&Al[r1 * 64 + ((cg ^ (r1 & 7)) << 3)];
                int r2 = wn + i * 16 + lrow;
                bb[i] = *(const bf16x8*)&Bl[r2 * 64 + ((cg ^ (r2 & 7)) << 3)];
            }
            #pragma unroll
            for (int i = 0; i < 4; i++)
                #pragma unroll
                for (int j = 0; j < 4; j++)
                    acc[i][j] = __builtin_amdgcn_mfma_f32_16x16x32_bf16(a[i], bb[j], acc[i][j], 0, 0, 0);
        }
        __syncthreads();
    }
    // epilogue: fp32 stores, 16-lane e-contiguous (64B segments)
    #pragma unroll
    for (int i = 0; i < 4; i++)
        #pragma unroll
        for (int t = 0; t < 4; t++) {
            int d = d0 + wm + i * 16 + lkg * 4 + t;
            int row = ((d >> 3) << 10) + ((d & 7) << 7) + b;
            float* dst = jac + (size_t)row * kD + e0 + wn;
            #pragma unroll
            for (int j = 0; j < 4; j++)
                dst[j * 16 + lrow] = acc[i][j][t];
        }
}

extern "C" void kernel_launch(void* const* d_in, const int* in_sizes, int n_in,
                              void* d_out, int out_size, void* d_ws, size_t ws_size,
                              hipStream_t stream) {
    const float* x  = (const float*)d_in[0];   // [128,1024]
    const float* W1 = (const float*)d_in[1];   // [512,1024]
    const float* b1 = (const float*)d_in[2];   // [512]
    const float* W2 = (const float*)d_in[3];   // [256,512]
    const float* b2 = (const float*)d_in[4];   // [256]
    const float* b3 = (const float*)d_in[5];   // [512]
    const float* br = (const float*)d_in[6];   // [1024]
    float* out = (float*)d_out;

    // workspace layout (float units); total ~21.8 MB
    float* p = (float*)d_ws;
    float* W1t = p; p += 524288;               // [1024][512] fp32 (fwd layer 1)
    float* W2t = p; p += 131072;               // [512][256]  fp32 (fwd layer 2)
    float* c1  = p; p += 65536;
    float* s1  = p; p += 65536;
    float* c2  = p; p += 32768;
    float* s2  = p; p += 32768;
    float* c3  = p; p += 65536;
    float* s3  = p; p += 65536;
    bf16* W1tb = (bf16*)p; p += 262144;        // [1024][512] bf16 (vm A operand)
    bf16* Vt   = (bf16*)p; p += (size_t)kChunk * kD * kH2 / 2;  // [chunk][1024][256]
    bf16* Mt   = (bf16*)p;

    float* recover = out;                        // [128,1024]
    float* c2_out  = out + kB * kD;              // [128,256]
    float* jac     = out + kB * kD + kB * kH2;   // [128,1024,1024] (permuted rows)

    transpose_kernel<<<dim3(kD / 32, kH1 / 32), 256, 0, stream>>>(W1, W1t, W1tb, kH1, kD);
    transpose_kernel<<<dim3(kH1 / 32, kH2 / 32), 256, 0, stream>>>(W2, W2t, nullptr, kH2, kH1);

    // forward pass (fp32, unchanged)
    fwd_kernel<<<dim3((kH1 + 255) / 256, kB), 256, 0, stream>>>(x,  W1t, b1, kD,  kH1, c1, nullptr, s1);
    fwd_kernel<<<dim3((kH2 + 255) / 256, kB), 256, 0, stream>>>(c1, W2t, b2, kH1, kH2, c2, c2_out, s2);
    fwd_kernel<<<dim3((kH1 + 255) / 256, kB), 256, 0, stream>>>(c2, W2,  b3, kH2, kH1, c3, nullptr, s3);
    fwd_kernel<<<dim3((kD  + 255) / 256, kB), 256, 0, stream>>>(c3, W1,  br, kH1, kD,  recover, nullptr, nullptr);

    for (int b0 = 0; b0 < kB; b0 += kChunk) {
        vm_mfma_kernel<<<dim3(kD / 128, kH2 / 64, kChunk), 256, 0, stream>>>(
            W1tb, W2, s1, s2, s3, Vt, Mt, b0);
        jac_mfma_kernel<<<dim3(kD / 128, kD / 128, kChunk), 256, 0, stream>>>(
            Vt, Mt, jac, b0);
    }
}